// Round 17
// baseline (148.792 us; speedup 1.0000x reference)
//
#include <hip/hip_runtime.h>
#include <hip/hip_bf16.h>
#include <math.h>

// FPLayer: 3-NN inverse-distance interpolation + concat + 2x (Conv1d(k=1) -> BN(train) -> ReLU)
// B=8 N1=8192 N2=2048 C1=128 C2=256 MLP=[256,128]
// Round 17: knn = QPT=2 + hybrid insert + NCHUNK=8 (one LDS read serves 2 queries;
//           single-branch flat insert per query; 1024 blocks keep 16 waves/CU).
//           Rest identical to r16 (XCD-swizzled fused gemm0, de-aliased buffers).

#define NB 8
#define NP1 8192
#define NP2 2048
#define C1 128
#define C2 256
#define KC (C1 + C2)    // 384
#define H0 256
#define H1 128
#define MT (NB * NP1)   // 65536 rows
#define GM (MT / 128)   // 512 m-tiles
#define BN_EPS 1e-5f
#define NCHUNK 8
#define CHSZ (NP2 / NCHUNK)   // 256
#define QPT 2
#define LP 72           // padded LDS K-stride (ushorts): 144B rows -> 2-way bank alias (free)

typedef __attribute__((ext_vector_type(8))) short bf16x8;
typedef __attribute__((ext_vector_type(4))) float f32x4;
typedef __attribute__((ext_vector_type(8))) unsigned short ushort8v;
typedef __attribute__((ext_vector_type(4))) unsigned short ushort4v;

__device__ __forceinline__ unsigned short bf16_rne(float x) {
  unsigned int u = __float_as_uint(x);
  u += 0x7FFFu + ((u >> 16) & 1u);   // round-to-nearest-even on bf16 boundary
  return (unsigned short)(u >> 16);
}
__device__ __forceinline__ float bf16_to_f32(unsigned short u) {
  return __uint_as_float(((unsigned int)u) << 16);
}

// ---------------- KNN phase 1: per-chunk top-3, QPT=2, hybrid insert, fma dist ----------------
// grid (NP1/(256*QPT)=16, NB, NCHUNK=8) = 1024 blocks, 256 thr.
__global__ __launch_bounds__(256) void knn_chunk_kernel(
    const float* __restrict__ xyz1, const float* __restrict__ xyz2,
    float2* __restrict__ cand)
{
  __shared__ __align__(16) float4 s2[CHSZ];   // {x, y, z, |p|^2/2}  4 KB
  const int b = blockIdx.y, c = blockIdx.z;
  const float* p2 = xyz2 + ((size_t)b * NP2 + c * CHSZ) * 3;
  {
    const int j = threadIdx.x;   // CHSZ == blockDim
    float x = p2[j * 3 + 0], y = p2[j * 3 + 1], z = p2[j * 3 + 2];
    float sq = __fadd_rn(__fadd_rn(__fmul_rn(x, x), __fmul_rn(y, y)), __fmul_rn(z, z));
    s2[j] = make_float4(x, y, z, 0.5f * sq);   // /2 exact
  }
  __syncthreads();
  const int n0 = blockIdx.x * (256 * QPT) + threadIdx.x;   // queries n0 + 256*q
  float ax[QPT], ay[QPT], az[QPT], hq[QPT];
  float b0v[QPT], b1v[QPT], b2v[QPT];
  int i0[QPT], i1[QPT], i2[QPT];
  #pragma unroll
  for (int q = 0; q < QPT; ++q) {
    const float* p1 = xyz1 + ((size_t)b * NP1 + n0 + 256 * q) * 3;
    ax[q] = p1[0]; ay[q] = p1[1]; az[q] = p1[2];
    const float sq1 = __fadd_rn(__fadd_rn(__fmul_rn(ax[q], ax[q]), __fmul_rn(ay[q], ay[q])),
                                __fmul_rn(az[q], az[q]));
    hq[q] = 0.5f * sq1;   // exact
    b0v[q] = 3.4e38f; b1v[q] = 3.4e38f; b2v[q] = 3.4e38f;
    i0[q] = 0; i1[q] = 0; i2[q] = 0;
  }
  #pragma unroll 2
  for (int j = 0; j < CHSZ; ++j) {
    const float4 p = s2[j];
    #pragma unroll
    for (int q = 0; q < QPT; ++q) {
      // fma-chain halved distance (4 VALU; selection-compatible, validated r10-r16)
      float m = __fadd_rn(hq[q], p.w);
      m = fmaf(-az[q], p.z, m);
      m = fmaf(-ay[q], p.y, m);
      m = fmaf(-ax[q], p.x, m);
      if (m < b2v[q]) {   // hybrid: single branch, flat predicated body (r9-proven)
        const bool lt1 = m < b1v[q], lt0 = m < b0v[q];
        b2v[q] = lt1 ? b1v[q] : m;
        i2[q]  = lt1 ? i1[q]  : j;
        b1v[q] = lt0 ? b0v[q] : (lt1 ? m : b1v[q]);
        i1[q]  = lt0 ? i0[q]  : (lt1 ? j : i1[q]);
        b0v[q] = lt0 ? m : b0v[q];
        i0[q]  = lt0 ? j : i0[q];
      }
    }
  }
  const int jb = c * CHSZ;
  #pragma unroll
  for (int q = 0; q < QPT; ++q) {
    const size_t o = (((size_t)b * NP1 + n0 + 256 * q) * NCHUNK + c) * 3;
    cand[o + 0] = make_float2(b0v[q], __int_as_float(jb + i0[q]));
    cand[o + 1] = make_float2(b1v[q], __int_as_float(jb + i1[q]));
    cand[o + 2] = make_float2(b2v[q], __int_as_float(jb + i2[q]));
  }
}

// ---------------- KNN phase 2: merge 8x3 candidates, compute weights ----------------
__global__ __launch_bounds__(256) void knn_merge_kernel(
    const float2* __restrict__ cand, int* __restrict__ knn_idx, float* __restrict__ knn_w)
{
  const int m = blockIdx.x * 256 + threadIdx.x;
  const float2* cc = cand + (size_t)m * (NCHUNK * 3);
  float b0v = 3.4e38f, b1v = 3.4e38f, b2v = 3.4e38f;
  int i0 = 0, i1 = 0, i2 = 0;
  #pragma unroll
  for (int t = 0; t < NCHUNK * 3; ++t) {
    const float2 p = cc[t];
    const float d2 = p.x;
    const int j = __float_as_int(p.y);
    if (d2 < b2v) {
      if (d2 < b1v) {
        b2v = b1v; i2 = i1;
        if (d2 < b0v) { b1v = b0v; i1 = i0; b0v = d2; i0 = j; }
        else          { b1v = d2; i1 = j; }
      } else { b2v = d2; i2 = j; }
    }
  }
  // restore d2 = 2*m (exact) and apply the reference clamp before sqrt
  const float d0 = fmaxf(__fmul_rn(2.0f, b0v), 1e-12f);
  const float d1 = fmaxf(__fmul_rn(2.0f, b1v), 1e-12f);
  const float d2v = fmaxf(__fmul_rn(2.0f, b2v), 1e-12f);
  const float s0 = sqrtf(d0), s1 = sqrtf(d1), s2d = sqrtf(d2v);
  const float r0 = 1.0f / (s0 + 1e-8f), r1 = 1.0f / (s1 + 1e-8f), r2 = 1.0f / (s2d + 1e-8f);
  const float rs = __fadd_rn(__fadd_rn(r0, r1), r2);
  const size_t o = (size_t)m * 3;
  knn_idx[o] = i0; knn_idx[o + 1] = i1; knn_idx[o + 2] = i2;
  knn_w[o] = r0 / rs; knn_w[o + 1] = r1 / rs; knn_w[o + 2] = r2 / rs;
}

// ---------------- both weights fp32 -> bf16 in one launch ----------------
__global__ __launch_bounds__(256) void cast_both_kernel(
    const float* __restrict__ W0, const float* __restrict__ W1,
    unsigned short* __restrict__ w0b, unsigned short* __restrict__ w1b)
{
  const int i = blockIdx.x * 256 + threadIdx.x;
  const int n0 = H0 * KC / 8;   // 12288
  const float* src; unsigned short* dst; int k;
  if (i < n0) { src = W0; dst = w0b; k = i; }
  else        { src = W1; dst = w1b; k = i - n0; }   // n1 = 4096
  const float4 a = ((const float4*)src)[2 * k], b = ((const float4*)src)[2 * k + 1];
  ushort8v u;
  u[0] = bf16_rne(a.x); u[1] = bf16_rne(a.y); u[2] = bf16_rne(a.z); u[3] = bf16_rne(a.w);
  u[4] = bf16_rne(b.x); u[5] = bf16_rne(b.y); u[6] = bf16_rne(b.z); u[7] = bf16_rne(b.w);
  *(ushort8v*)(dst + (size_t)k * 8) = u;
}

// ---------------- GEMM0: y0 = [feat1 | interp(feat2)] @ W0^T + b0, 128x256 tile, 8 waves ----
// grid (GM). XCD-swizzled: tm = (l&7)*64 + l>>3  (512%8==0 -> bijective). Batch b's 64
// m-tiles land on XCD b -> feat2 gathers stay in that XCD's 4MB L2 (2MB slice).
__global__ __launch_bounds__(512) void gemm0_mfma_kernel(
    const float* __restrict__ feat1, const float* __restrict__ feat2,
    const int* __restrict__ knn_idx, const float* __restrict__ knn_w,
    const unsigned short* __restrict__ w0b, const float* __restrict__ b0,
    unsigned short* __restrict__ y0b, float2* __restrict__ part0)
{
  __shared__ __align__(16) unsigned short As[128][LP];   // 18.4 KB
  __shared__ __align__(16) unsigned short Bs[256][LP];   // 36.9 KB
  __shared__ float sredS[8][64], sredQ[8][64];           // 4 KB
  const int l = blockIdx.x;
  const int tm = (l & 7) * (GM / 8) + (l >> 3);   // XCD-aware bijective swizzle
  const int tid = threadIdx.x, lane = tid & 63, w = tid >> 6;
  const int wr = w >> 2, wc = w & 3;
  const int row0 = tm * 128;
  const int seg = tid & 7, rt = tid >> 3;   // rt in [0,64)
  const int ln = lane & 15, lg = lane >> 4;

  // per-thread gather state for its 2 staged A-rows
  unsigned g0[2], g1[2], g2[2];
  float gw0[2], gw1[2], gw2[2];
  #pragma unroll
  for (int p = 0; p < 2; ++p) {
    const int grow = row0 + rt + 64 * p;
    const size_t o3 = (size_t)grow * 3;
    const unsigned base = (unsigned)(grow >> 13) * (NP2 * C2);
    g0[p] = base + (unsigned)knn_idx[o3]     * C2;
    g1[p] = base + (unsigned)knn_idx[o3 + 1] * C2;
    g2[p] = base + (unsigned)knn_idx[o3 + 2] * C2;
    gw0[p] = knn_w[o3]; gw1[p] = knn_w[o3 + 1]; gw2[p] = knn_w[o3 + 2];
  }

  f32x4 acc[4][4] = {};
  for (int k0 = 0; k0 < KC; k0 += 64) {
    if (k0 < C1) {   // feat1 fp32 -> bf16 staging (2 rows/thread)
      #pragma unroll
      for (int p = 0; p < 2; ++p) {
        const int r = rt + 64 * p;
        const float* src = feat1 + (size_t)(row0 + r) * C1 + k0 + seg * 8;
        const float4 va = *(const float4*)src, vb = *(const float4*)(src + 4);
        ushort8v u;
        u[0] = bf16_rne(va.x); u[1] = bf16_rne(va.y); u[2] = bf16_rne(va.z); u[3] = bf16_rne(va.w);
        u[4] = bf16_rne(vb.x); u[5] = bf16_rne(vb.y); u[6] = bf16_rne(vb.z); u[7] = bf16_rne(vb.w);
        *(ushort8v*)&As[r][seg * 8] = u;
      }
    } else {         // fused interp staging: gather 3 neighbor rows, weight, cast
      const int ch = (k0 - C1) + seg * 8;
      #pragma unroll
      for (int p = 0; p < 2; ++p) {
        const int r = rt + 64 * p;
        const float4* f0p = (const float4*)(feat2 + (size_t)g0[p] + ch);
        const float4* f1p = (const float4*)(feat2 + (size_t)g1[p] + ch);
        const float4* f2p = (const float4*)(feat2 + (size_t)g2[p] + ch);
        const float4 a0 = f0p[0], a1 = f0p[1];
        const float4 e0 = f1p[0], e1 = f1p[1];
        const float4 c0 = f2p[0], c1 = f2p[1];
        const float w0v = gw0[p], w1v = gw1[p], w2v = gw2[p];
        ushort8v u;
        u[0] = bf16_rne(w0v * a0.x + w1v * e0.x + w2v * c0.x);
        u[1] = bf16_rne(w0v * a0.y + w1v * e0.y + w2v * c0.y);
        u[2] = bf16_rne(w0v * a0.z + w1v * e0.z + w2v * c0.z);
        u[3] = bf16_rne(w0v * a0.w + w1v * e0.w + w2v * c0.w);
        u[4] = bf16_rne(w0v * a1.x + w1v * e1.x + w2v * c1.x);
        u[5] = bf16_rne(w0v * a1.y + w1v * e1.y + w2v * c1.y);
        u[6] = bf16_rne(w0v * a1.z + w1v * e1.z + w2v * c1.z);
        u[7] = bf16_rne(w0v * a1.w + w1v * e1.w + w2v * c1.w);
        *(ushort8v*)&As[r][seg * 8] = u;
      }
    }
    // B staging: 4 rows/thread (256 output channels)
    #pragma unroll
    for (int p = 0; p < 4; ++p) {
      const int r = rt + 64 * p;
      *(uint4*)&Bs[r][seg * 8] = *(const uint4*)(w0b + (size_t)r * KC + k0 + seg * 8);
    }
    __syncthreads();
    #pragma unroll
    for (int kb = 0; kb < 2; ++kb) {
      bf16x8 af[4], bf[4];
      #pragma unroll
      for (int i = 0; i < 4; ++i)
        af[i] = *(const bf16x8*)&As[wr * 64 + i * 16 + ln][kb * 32 + lg * 8];
      #pragma unroll
      for (int j = 0; j < 4; ++j)
        bf[j] = *(const bf16x8*)&Bs[wc * 64 + j * 16 + ln][kb * 32 + lg * 8];
      #pragma unroll
      for (int i = 0; i < 4; ++i)
        #pragma unroll
        for (int j = 0; j < 4; ++j)
          acc[i][j] = __builtin_amdgcn_mfma_f32_16x16x32_bf16(af[i], bf[j], acc[i][j], 0, 0, 0);
    }
    __syncthreads();
  }
  // epilogue: bias, store y0 bf16, per-column BN partials from fp32 values
  float colS[4] = {0, 0, 0, 0}, colQ[4] = {0, 0, 0, 0};
  #pragma unroll
  for (int j = 0; j < 4; ++j) {
    const int gc = wc * 64 + j * 16 + ln;
    const float bias = b0[gc];
    #pragma unroll
    for (int i = 0; i < 4; ++i) {
      const int grow = row0 + wr * 64 + i * 16 + lg * 4;
      #pragma unroll
      for (int q = 0; q < 4; ++q) {
        const float v = acc[i][j][q] + bias;
        y0b[(size_t)(grow + q) * H0 + gc] = bf16_rne(v);
        colS[j] += v; colQ[j] = fmaf(v, v, colQ[j]);
      }
    }
  }
  #pragma unroll
  for (int j = 0; j < 4; ++j) {
    colS[j] += __shfl_xor(colS[j], 16, 64);
    colS[j] += __shfl_xor(colS[j], 32, 64);
    colQ[j] += __shfl_xor(colQ[j], 16, 64);
    colQ[j] += __shfl_xor(colQ[j], 32, 64);
  }
  if (lg == 0) {
    #pragma unroll
    for (int j = 0; j < 4; ++j) { sredS[w][j * 16 + ln] = colS[j]; sredQ[w][j * 16 + ln] = colQ[j]; }
  }
  __syncthreads();
  if (tid < 256) {   // column = tid; combine wr=0 and wr=1 partials
    const int wcc = tid >> 6, cl = tid & 63;
    const float S = sredS[wcc][cl] + sredS[4 + wcc][cl];
    const float Q = sredQ[wcc][cl] + sredQ[4 + wcc][cl];
    part0[(size_t)tid * GM + tm] = make_float2(S, Q);
  }
}

// ---------------- BN finalize: mean/var -> scale/shift ----------------
__global__ __launch_bounds__(256) void bnfin_kernel(
    const float2* __restrict__ part, const float* __restrict__ gamma,
    const float* __restrict__ beta, float* __restrict__ sc, float* __restrict__ sh)
{
  __shared__ float2 red[256];
  const int ch = blockIdx.x, tid = threadIdx.x;
  float s = 0.f, q = 0.f;
  for (int t = tid; t < GM; t += 256) {
    float2 p = part[(size_t)ch * GM + t];
    s += p.x; q += p.y;
  }
  red[tid] = make_float2(s, q);
  __syncthreads();
  for (int off = 128; off > 0; off >>= 1) {
    if (tid < off) { float2 o = red[tid + off]; red[tid].x += o.x; red[tid].y += o.y; }
    __syncthreads();
  }
  if (tid == 0) {
    const float mean = red[0].x / (float)MT;
    const float var  = red[0].y / (float)MT - mean * mean;
    const float scale = gamma[ch] / sqrtf(var + BN_EPS);
    sc[ch] = scale;
    sh[ch] = beta[ch] - mean * scale;
  }
}

// ---------------- GEMM1: y1 = relu(bn0(y0)) @ W1^T + b1 (bf16 MFMA), y1 stored bf16 ----------------
// grid (1, 512). BN0+ReLU+bf16-cast fused into A staging; y0 read as bf16.
__global__ __launch_bounds__(256) void gemm1_mfma_kernel(
    const unsigned short* __restrict__ y0b, const float* __restrict__ sc0, const float* __restrict__ sh0,
    const unsigned short* __restrict__ w1b, const float* __restrict__ b1,
    unsigned short* __restrict__ y1, float2* __restrict__ part1)
{
  __shared__ __align__(16) unsigned short As[128][LP];
  __shared__ __align__(16) unsigned short Bs[128][LP];
  __shared__ float sredS[4][64], sredQ[4][64];
  const int tm = blockIdx.y;
  const int tid = threadIdx.x, lane = tid & 63, w = tid >> 6;
  const int wr = w >> 1, wc = w & 1;
  const int row0 = tm * 128;
  const int seg = tid & 7, rt = tid >> 3;
  const int ln = lane & 15, lg = lane >> 4;
  f32x4 acc[4][4] = {};
  for (int k0 = 0; k0 < H0; k0 += 64) {
    const float4 sA = *(const float4*)(sc0 + k0 + seg * 8);
    const float4 sB = *(const float4*)(sc0 + k0 + seg * 8 + 4);
    const float4 hA = *(const float4*)(sh0 + k0 + seg * 8);
    const float4 hB = *(const float4*)(sh0 + k0 + seg * 8 + 4);
    #pragma unroll
    for (int p = 0; p < 4; ++p) {
      const int r = rt + 32 * p;
      const ushort8v uy = *(const ushort8v*)(y0b + (size_t)(row0 + r) * H0 + k0 + seg * 8);
      ushort8v u;
      u[0] = bf16_rne(fmaxf(fmaf(bf16_to_f32(uy[0]), sA.x, hA.x), 0.f));
      u[1] = bf16_rne(fmaxf(fmaf(bf16_to_f32(uy[1]), sA.y, hA.y), 0.f));
      u[2] = bf16_rne(fmaxf(fmaf(bf16_to_f32(uy[2]), sA.z, hA.z), 0.f));
      u[3] = bf16_rne(fmaxf(fmaf(bf16_to_f32(uy[3]), sA.w, hA.w), 0.f));
      u[4] = bf16_rne(fmaxf(fmaf(bf16_to_f32(uy[4]), sB.x, hB.x), 0.f));
      u[5] = bf16_rne(fmaxf(fmaf(bf16_to_f32(uy[5]), sB.y, hB.y), 0.f));
      u[6] = bf16_rne(fmaxf(fmaf(bf16_to_f32(uy[6]), sB.z, hB.z), 0.f));
      u[7] = bf16_rne(fmaxf(fmaf(bf16_to_f32(uy[7]), sB.w, hB.w), 0.f));
      *(ushort8v*)&As[r][seg * 8] = u;
      *(uint4*)&Bs[r][seg * 8] = *(const uint4*)(w1b + (size_t)r * H0 + k0 + seg * 8);
    }
    __syncthreads();
    #pragma unroll
    for (int kb = 0; kb < 2; ++kb) {
      bf16x8 af[4], bf[4];
      #pragma unroll
      for (int i = 0; i < 4; ++i)
        af[i] = *(const bf16x8*)&As[wr * 64 + i * 16 + ln][kb * 32 + lg * 8];
      #pragma unroll
      for (int j = 0; j < 4; ++j)
        bf[j] = *(const bf16x8*)&Bs[wc * 64 + j * 16 + ln][kb * 32 + lg * 8];
      #pragma unroll
      for (int i = 0; i < 4; ++i)
        #pragma unroll
        for (int j = 0; j < 4; ++j)
          acc[i][j] = __builtin_amdgcn_mfma_f32_16x16x32_bf16(af[i], bf[j], acc[i][j], 0, 0, 0);
    }
    __syncthreads();
  }
  float colS[4] = {0, 0, 0, 0}, colQ[4] = {0, 0, 0, 0};
  #pragma unroll
  for (int j = 0; j < 4; ++j) {
    const int gc = wc * 64 + j * 16 + ln;
    const float bias = b1[gc];
    #pragma unroll
    for (int i = 0; i < 4; ++i) {
      const int grow = row0 + wr * 64 + i * 16 + lg * 4;
      #pragma unroll
      for (int q = 0; q < 4; ++q) {
        const float v = acc[i][j][q] + bias;
        y1[(size_t)(grow + q) * H1 + gc] = bf16_rne(v);
        colS[j] += v; colQ[j] = fmaf(v, v, colQ[j]);
      }
    }
  }
  #pragma unroll
  for (int j = 0; j < 4; ++j) {
    colS[j] += __shfl_xor(colS[j], 16, 64);
    colS[j] += __shfl_xor(colS[j], 32, 64);
    colQ[j] += __shfl_xor(colQ[j], 16, 64);
    colQ[j] += __shfl_xor(colQ[j], 32, 64);
  }
  if (lg == 0) {
    #pragma unroll
    for (int j = 0; j < 4; ++j) { sredS[w][j * 16 + ln] = colS[j]; sredQ[w][j * 16 + ln] = colQ[j]; }
  }
  __syncthreads();
  if (tid < 128) {
    const int ch = tid >> 6, cl = tid & 63;
    const float S = sredS[ch][cl] + sredS[2 + ch][cl];
    const float Q = sredQ[ch][cl] + sredQ[2 + ch][cl];
    part1[(size_t)tid * GM + tm] = make_float2(S, Q);
  }
}

// ---------------- Final BN1 + ReLU (bf16 y1 -> fp32 out) ----------------
__global__ __launch_bounds__(256) void bnrelu_out_kernel(
    const unsigned short* __restrict__ y1, const float* __restrict__ sc1,
    const float* __restrict__ sh1, float* __restrict__ out)
{
  const size_t i = (size_t)blockIdx.x * 256 + threadIdx.x;  // ushort8 unit (8 channels)
  const int c8 = (int)(i & (H1 / 8 - 1));
  const ushort8v u = ((const ushort8v*)y1)[i];
  const float4 s0 = ((const float4*)sc1)[c8 * 2], s1 = ((const float4*)sc1)[c8 * 2 + 1];
  const float4 h0 = ((const float4*)sh1)[c8 * 2], h1 = ((const float4*)sh1)[c8 * 2 + 1];
  float4 o0, o1;
  o0.x = fmaxf(fmaf(bf16_to_f32(u[0]), s0.x, h0.x), 0.f);
  o0.y = fmaxf(fmaf(bf16_to_f32(u[1]), s0.y, h0.y), 0.f);
  o0.z = fmaxf(fmaf(bf16_to_f32(u[2]), s0.z, h0.z), 0.f);
  o0.w = fmaxf(fmaf(bf16_to_f32(u[3]), s0.w, h0.w), 0.f);
  o1.x = fmaxf(fmaf(bf16_to_f32(u[4]), s1.x, h1.x), 0.f);
  o1.y = fmaxf(fmaf(bf16_to_f32(u[5]), s1.y, h1.y), 0.f);
  o1.z = fmaxf(fmaf(bf16_to_f32(u[6]), s1.z, h1.z), 0.f);
  o1.w = fmaxf(fmaf(bf16_to_f32(u[7]), s1.w, h1.w), 0.f);
  ((float4*)out)[2 * i] = o0;
  ((float4*)out)[2 * i + 1] = o1;
}

extern "C" void kernel_launch(void* const* d_in, const int* in_sizes, int n_in,
                              void* d_out, int out_size, void* d_ws, size_t ws_size,
                              hipStream_t stream)
{
  const float* xyz1  = (const float*)d_in[0];
  const float* xyz2  = (const float*)d_in[1];
  const float* feat1 = (const float*)d_in[2];
  const float* feat2 = (const float*)d_in[3];
  const float* W0  = (const float*)d_in[4];
  const float* b0  = (const float*)d_in[5];
  const float* g0  = (const float*)d_in[6];
  const float* be0 = (const float*)d_in[7];
  const float* W1  = (const float*)d_in[8];
  const float* b1  = (const float*)d_in[9];
  const float* g1  = (const float*)d_in[10];
  const float* be1 = (const float*)d_in[11];
  float* out = (float*)d_out;

  // workspace layout (~66 MB) — every buffer has exactly ONE writer kernel (no aliasing)
  char* ws = (char*)d_ws;
  size_t off = 0;
  unsigned short* y0b = (unsigned short*)(ws + off); off += (size_t)MT * H0 * 2;      // 33.5 MB
  unsigned short* y1  = (unsigned short*)(ws + off); off += (size_t)MT * H1 * 2;      // 16.8 MB
  float2* cand = (float2*)(ws + off); off += (size_t)MT * NCHUNK * 3 * 8;             // 12.6 MB
  int*   kidx = (int*)(ws + off);  off += (size_t)MT * 3 * 4;
  float* kw   = (float*)(ws + off); off += (size_t)MT * 3 * 4;
  float2* part0 = (float2*)(ws + off); off += (size_t)H0 * GM * 8;
  float2* part1 = (float2*)(ws + off); off += (size_t)H1 * GM * 8;
  unsigned short* w0b = (unsigned short*)(ws + off); off += (size_t)H0 * KC * 2;
  unsigned short* w1b = (unsigned short*)(ws + off); off += (size_t)H1 * H0 * 2;
  float* sc0 = (float*)(ws + off); off += H0 * 4;
  float* sh0 = (float*)(ws + off); off += H0 * 4;
  float* sc1 = (float*)(ws + off); off += H1 * 4;
  float* sh1 = (float*)(ws + off); off += H1 * 4;

  knn_chunk_kernel<<<dim3(NP1 / (256 * QPT), NB, NCHUNK), 256, 0, stream>>>(xyz1, xyz2, cand);
  knn_merge_kernel<<<dim3(MT / 256), 256, 0, stream>>>(cand, kidx, kw);
  cast_both_kernel<<<dim3((H0 * KC / 8 + H1 * H0 / 8) / 256), 256, 0, stream>>>(W0, W1, w0b, w1b);
  gemm0_mfma_kernel<<<dim3(GM), 512, 0, stream>>>(feat1, feat2, kidx, kw, w0b, b0, y0b, part0);
  bnfin_kernel<<<dim3(H0), 256, 0, stream>>>(part0, g0, be0, sc0, sh0);
  gemm1_mfma_kernel<<<dim3(1, GM), 256, 0, stream>>>(y0b, sc0, sh0, w1b, b1, y1, part1);
  bnfin_kernel<<<dim3(H1), 256, 0, stream>>>(part1, g1, be1, sc1, sh1);
  bnrelu_out_kernel<<<dim3(MT * H1 / 8 / 256), 256, 0, stream>>>(y1, sc1, sh1, out);
}

// Round 18
// 131.387 us; speedup vs baseline: 1.1325x; 1.1325x over previous
//
#include <hip/hip_runtime.h>
#include <hip/hip_bf16.h>
#include <math.h>

// FPLayer: 3-NN inverse-distance interpolation + concat + 2x (Conv1d(k=1) -> BN(train) -> ReLU)
// B=8 N1=8192 N2=2048 C1=128 C2=256 MLP=[256,128]
// Round 18: knn = r16 exact (57.4us proven floor). gemm1 gets the same XCD swizzle as
//           gemm0 (y0b L2 reuse); knn_merge + cast_both fused into one launch.

#define NB 8
#define NP1 8192
#define NP2 2048
#define C1 128
#define C2 256
#define KC (C1 + C2)    // 384
#define H0 256
#define H1 128
#define MT (NB * NP1)   // 65536 rows
#define GM (MT / 128)   // 512 m-tiles
#define BN_EPS 1e-5f
#define NCHUNK 4
#define CHSZ (NP2 / NCHUNK)   // 512
#define LP 72           // padded LDS K-stride (ushorts): 144B rows -> 2-way bank alias (free)

typedef __attribute__((ext_vector_type(8))) short bf16x8;
typedef __attribute__((ext_vector_type(4))) float f32x4;
typedef __attribute__((ext_vector_type(8))) unsigned short ushort8v;
typedef __attribute__((ext_vector_type(4))) unsigned short ushort4v;

__device__ __forceinline__ unsigned short bf16_rne(float x) {
  unsigned int u = __float_as_uint(x);
  u += 0x7FFFu + ((u >> 16) & 1u);   // round-to-nearest-even on bf16 boundary
  return (unsigned short)(u >> 16);
}
__device__ __forceinline__ float bf16_to_f32(unsigned short u) {
  return __uint_as_float(((unsigned int)u) << 16);
}

// ---------------- KNN phase 1: per-chunk top-3 candidates (hybrid insert, fma dist) ----------------
__global__ __launch_bounds__(256) void knn_chunk_kernel(
    const float* __restrict__ xyz1, const float* __restrict__ xyz2,
    float2* __restrict__ cand)
{
  __shared__ __align__(16) float4 s2[CHSZ];   // {x, y, z, |p|^2/2}  8 KB
  const int b = blockIdx.y, c = blockIdx.z;
  const float* p2 = xyz2 + ((size_t)b * NP2 + c * CHSZ) * 3;
  for (int j = threadIdx.x; j < CHSZ; j += 256) {
    float x = p2[j * 3 + 0], y = p2[j * 3 + 1], z = p2[j * 3 + 2];
    float sq = __fadd_rn(__fadd_rn(__fmul_rn(x, x), __fmul_rn(y, y)), __fmul_rn(z, z));
    s2[j] = make_float4(x, y, z, 0.5f * sq);   // /2 exact
  }
  __syncthreads();
  const int n = blockIdx.x * 256 + threadIdx.x;
  const float* p1 = xyz1 + ((size_t)b * NP1 + n) * 3;
  const float ax = p1[0], ay = p1[1], az = p1[2];
  const float sq1 = __fadd_rn(__fadd_rn(__fmul_rn(ax, ax), __fmul_rn(ay, ay)), __fmul_rn(az, az));
  const float hsq1 = 0.5f * sq1;   // exact
  float b0v = 3.4e38f, b1v = 3.4e38f, b2v = 3.4e38f;
  int i0 = 0, i1 = 0, i2 = 0;
  #pragma unroll 4
  for (int j = 0; j < CHSZ; ++j) {
    const float4 p = s2[j];
    // fma-chain halved distance (4 VALU; selection-compatible, validated r10-r16)
    float m = __fadd_rn(hsq1, p.w);
    m = fmaf(-az, p.z, m);
    m = fmaf(-ay, p.y, m);
    m = fmaf(-ax, p.x, m);
    if (m < b2v) {
      const bool lt1 = m < b1v, lt0 = m < b0v;
      b2v = lt1 ? b1v : m;
      i2  = lt1 ? i1  : j;
      b1v = lt0 ? b0v : (lt1 ? m : b1v);
      i1  = lt0 ? i0  : (lt1 ? j : i1);
      b0v = lt0 ? m : b0v;
      i0  = lt0 ? j : i0;
    }
  }
  const int jb = c * CHSZ;
  const size_t o = (((size_t)b * NP1 + n) * NCHUNK + c) * 3;
  cand[o + 0] = make_float2(b0v, __int_as_float(jb + i0));
  cand[o + 1] = make_float2(b1v, __int_as_float(jb + i1));
  cand[o + 2] = make_float2(b2v, __int_as_float(jb + i2));
}

// ---------------- fused: KNN merge (blocks 0..255) + weight casts (blocks 256..319) ----------------
__global__ __launch_bounds__(256) void merge_cast_kernel(
    const float2* __restrict__ cand, int* __restrict__ knn_idx, float* __restrict__ knn_w,
    const float* __restrict__ W0, const float* __restrict__ W1,
    unsigned short* __restrict__ w0b, unsigned short* __restrict__ w1b)
{
  const int tid = threadIdx.x;
  if (blockIdx.x < MT / 256) {
    // ---- merge 4x3 candidates, compute weights ----
    const int m = blockIdx.x * 256 + tid;
    const float2* cc = cand + (size_t)m * (NCHUNK * 3);
    float b0v = 3.4e38f, b1v = 3.4e38f, b2v = 3.4e38f;
    int i0 = 0, i1 = 0, i2 = 0;
    #pragma unroll
    for (int t = 0; t < NCHUNK * 3; ++t) {
      const float2 p = cc[t];
      const float d2 = p.x;
      const int j = __float_as_int(p.y);
      if (d2 < b2v) {
        if (d2 < b1v) {
          b2v = b1v; i2 = i1;
          if (d2 < b0v) { b1v = b0v; i1 = i0; b0v = d2; i0 = j; }
          else          { b1v = d2; i1 = j; }
        } else { b2v = d2; i2 = j; }
      }
    }
    // restore d2 = 2*m (exact) and apply the reference clamp before sqrt
    const float d0 = fmaxf(__fmul_rn(2.0f, b0v), 1e-12f);
    const float d1 = fmaxf(__fmul_rn(2.0f, b1v), 1e-12f);
    const float d2v = fmaxf(__fmul_rn(2.0f, b2v), 1e-12f);
    const float s0 = sqrtf(d0), s1 = sqrtf(d1), s2d = sqrtf(d2v);
    const float r0 = 1.0f / (s0 + 1e-8f), r1 = 1.0f / (s1 + 1e-8f), r2 = 1.0f / (s2d + 1e-8f);
    const float rs = __fadd_rn(__fadd_rn(r0, r1), r2);
    const size_t o = (size_t)m * 3;
    knn_idx[o] = i0; knn_idx[o + 1] = i1; knn_idx[o + 2] = i2;
    knn_w[o] = r0 / rs; knn_w[o + 1] = r1 / rs; knn_w[o + 2] = r2 / rs;
  } else {
    // ---- both weights fp32 -> bf16 ----
    const int i = (blockIdx.x - MT / 256) * 256 + tid;
    const int n0 = H0 * KC / 8;   // 12288
    const float* src; unsigned short* dst; int k;
    if (i < n0) { src = W0; dst = w0b; k = i; }
    else        { src = W1; dst = w1b; k = i - n0; }   // n1 = 4096
    const float4 a = ((const float4*)src)[2 * k], b = ((const float4*)src)[2 * k + 1];
    ushort8v u;
    u[0] = bf16_rne(a.x); u[1] = bf16_rne(a.y); u[2] = bf16_rne(a.z); u[3] = bf16_rne(a.w);
    u[4] = bf16_rne(b.x); u[5] = bf16_rne(b.y); u[6] = bf16_rne(b.z); u[7] = bf16_rne(b.w);
    *(ushort8v*)(dst + (size_t)k * 8) = u;
  }
}

// ---------------- GEMM0: y0 = [feat1 | interp(feat2)] @ W0^T + b0, 128x256 tile, 8 waves ----
// grid (GM). XCD-swizzled: tm = (l&7)*64 + l>>3  (512%8==0 -> bijective). Batch b's 64
// m-tiles land on XCD b -> feat2 gathers stay in that XCD's 4MB L2 (2MB slice).
__global__ __launch_bounds__(512) void gemm0_mfma_kernel(
    const float* __restrict__ feat1, const float* __restrict__ feat2,
    const int* __restrict__ knn_idx, const float* __restrict__ knn_w,
    const unsigned short* __restrict__ w0b, const float* __restrict__ b0,
    unsigned short* __restrict__ y0b, float2* __restrict__ part0)
{
  __shared__ __align__(16) unsigned short As[128][LP];   // 18.4 KB
  __shared__ __align__(16) unsigned short Bs[256][LP];   // 36.9 KB
  __shared__ float sredS[8][64], sredQ[8][64];           // 4 KB
  const int l = blockIdx.x;
  const int tm = (l & 7) * (GM / 8) + (l >> 3);   // XCD-aware bijective swizzle
  const int tid = threadIdx.x, lane = tid & 63, w = tid >> 6;
  const int wr = w >> 2, wc = w & 3;
  const int row0 = tm * 128;
  const int seg = tid & 7, rt = tid >> 3;   // rt in [0,64)
  const int ln = lane & 15, lg = lane >> 4;

  // per-thread gather state for its 2 staged A-rows
  unsigned g0[2], g1[2], g2[2];
  float gw0[2], gw1[2], gw2[2];
  #pragma unroll
  for (int p = 0; p < 2; ++p) {
    const int grow = row0 + rt + 64 * p;
    const size_t o3 = (size_t)grow * 3;
    const unsigned base = (unsigned)(grow >> 13) * (NP2 * C2);
    g0[p] = base + (unsigned)knn_idx[o3]     * C2;
    g1[p] = base + (unsigned)knn_idx[o3 + 1] * C2;
    g2[p] = base + (unsigned)knn_idx[o3 + 2] * C2;
    gw0[p] = knn_w[o3]; gw1[p] = knn_w[o3 + 1]; gw2[p] = knn_w[o3 + 2];
  }

  f32x4 acc[4][4] = {};
  for (int k0 = 0; k0 < KC; k0 += 64) {
    if (k0 < C1) {   // feat1 fp32 -> bf16 staging (2 rows/thread)
      #pragma unroll
      for (int p = 0; p < 2; ++p) {
        const int r = rt + 64 * p;
        const float* src = feat1 + (size_t)(row0 + r) * C1 + k0 + seg * 8;
        const float4 va = *(const float4*)src, vb = *(const float4*)(src + 4);
        ushort8v u;
        u[0] = bf16_rne(va.x); u[1] = bf16_rne(va.y); u[2] = bf16_rne(va.z); u[3] = bf16_rne(va.w);
        u[4] = bf16_rne(vb.x); u[5] = bf16_rne(vb.y); u[6] = bf16_rne(vb.z); u[7] = bf16_rne(vb.w);
        *(ushort8v*)&As[r][seg * 8] = u;
      }
    } else {         // fused interp staging: gather 3 neighbor rows, weight, cast
      const int ch = (k0 - C1) + seg * 8;
      #pragma unroll
      for (int p = 0; p < 2; ++p) {
        const int r = rt + 64 * p;
        const float4* f0p = (const float4*)(feat2 + (size_t)g0[p] + ch);
        const float4* f1p = (const float4*)(feat2 + (size_t)g1[p] + ch);
        const float4* f2p = (const float4*)(feat2 + (size_t)g2[p] + ch);
        const float4 a0 = f0p[0], a1 = f0p[1];
        const float4 e0 = f1p[0], e1 = f1p[1];
        const float4 c0 = f2p[0], c1 = f2p[1];
        const float w0v = gw0[p], w1v = gw1[p], w2v = gw2[p];
        ushort8v u;
        u[0] = bf16_rne(w0v * a0.x + w1v * e0.x + w2v * c0.x);
        u[1] = bf16_rne(w0v * a0.y + w1v * e0.y + w2v * c0.y);
        u[2] = bf16_rne(w0v * a0.z + w1v * e0.z + w2v * c0.z);
        u[3] = bf16_rne(w0v * a0.w + w1v * e0.w + w2v * c0.w);
        u[4] = bf16_rne(w0v * a1.x + w1v * e1.x + w2v * c1.x);
        u[5] = bf16_rne(w0v * a1.y + w1v * e1.y + w2v * c1.y);
        u[6] = bf16_rne(w0v * a1.z + w1v * e1.z + w2v * c1.z);
        u[7] = bf16_rne(w0v * a1.w + w1v * e1.w + w2v * c1.w);
        *(ushort8v*)&As[r][seg * 8] = u;
      }
    }
    // B staging: 4 rows/thread (256 output channels)
    #pragma unroll
    for (int p = 0; p < 4; ++p) {
      const int r = rt + 64 * p;
      *(uint4*)&Bs[r][seg * 8] = *(const uint4*)(w0b + (size_t)r * KC + k0 + seg * 8);
    }
    __syncthreads();
    #pragma unroll
    for (int kb = 0; kb < 2; ++kb) {
      bf16x8 af[4], bf[4];
      #pragma unroll
      for (int i = 0; i < 4; ++i)
        af[i] = *(const bf16x8*)&As[wr * 64 + i * 16 + ln][kb * 32 + lg * 8];
      #pragma unroll
      for (int j = 0; j < 4; ++j)
        bf[j] = *(const bf16x8*)&Bs[wc * 64 + j * 16 + ln][kb * 32 + lg * 8];
      #pragma unroll
      for (int i = 0; i < 4; ++i)
        #pragma unroll
        for (int j = 0; j < 4; ++j)
          acc[i][j] = __builtin_amdgcn_mfma_f32_16x16x32_bf16(af[i], bf[j], acc[i][j], 0, 0, 0);
    }
    __syncthreads();
  }
  // epilogue: bias, store y0 bf16, per-column BN partials from fp32 values
  float colS[4] = {0, 0, 0, 0}, colQ[4] = {0, 0, 0, 0};
  #pragma unroll
  for (int j = 0; j < 4; ++j) {
    const int gc = wc * 64 + j * 16 + ln;
    const float bias = b0[gc];
    #pragma unroll
    for (int i = 0; i < 4; ++i) {
      const int grow = row0 + wr * 64 + i * 16 + lg * 4;
      #pragma unroll
      for (int q = 0; q < 4; ++q) {
        const float v = acc[i][j][q] + bias;
        y0b[(size_t)(grow + q) * H0 + gc] = bf16_rne(v);
        colS[j] += v; colQ[j] = fmaf(v, v, colQ[j]);
      }
    }
  }
  #pragma unroll
  for (int j = 0; j < 4; ++j) {
    colS[j] += __shfl_xor(colS[j], 16, 64);
    colS[j] += __shfl_xor(colS[j], 32, 64);
    colQ[j] += __shfl_xor(colQ[j], 16, 64);
    colQ[j] += __shfl_xor(colQ[j], 32, 64);
  }
  if (lg == 0) {
    #pragma unroll
    for (int j = 0; j < 4; ++j) { sredS[w][j * 16 + ln] = colS[j]; sredQ[w][j * 16 + ln] = colQ[j]; }
  }
  __syncthreads();
  if (tid < 256) {   // column = tid; combine wr=0 and wr=1 partials
    const int wcc = tid >> 6, cl = tid & 63;
    const float S = sredS[wcc][cl] + sredS[4 + wcc][cl];
    const float Q = sredQ[wcc][cl] + sredQ[4 + wcc][cl];
    part0[(size_t)tid * GM + tm] = make_float2(S, Q);
  }
}

// ---------------- BN finalize: mean/var -> scale/shift ----------------
__global__ __launch_bounds__(256) void bnfin_kernel(
    const float2* __restrict__ part, const float* __restrict__ gamma,
    const float* __restrict__ beta, float* __restrict__ sc, float* __restrict__ sh)
{
  __shared__ float2 red[256];
  const int ch = blockIdx.x, tid = threadIdx.x;
  float s = 0.f, q = 0.f;
  for (int t = tid; t < GM; t += 256) {
    float2 p = part[(size_t)ch * GM + t];
    s += p.x; q += p.y;
  }
  red[tid] = make_float2(s, q);
  __syncthreads();
  for (int off = 128; off > 0; off >>= 1) {
    if (tid < off) { float2 o = red[tid + off]; red[tid].x += o.x; red[tid].y += o.y; }
    __syncthreads();
  }
  if (tid == 0) {
    const float mean = red[0].x / (float)MT;
    const float var  = red[0].y / (float)MT - mean * mean;
    const float scale = gamma[ch] / sqrtf(var + BN_EPS);
    sc[ch] = scale;
    sh[ch] = beta[ch] - mean * scale;
  }
}

// ---------------- GEMM1: y1 = relu(bn0(y0)) @ W1^T + b1 (bf16 MFMA), y1 stored bf16 ----------------
// grid (GM), XCD-swizzled like gemm0 so tile tm reads y0b from the XCD whose L2 holds it.
__global__ __launch_bounds__(256) void gemm1_mfma_kernel(
    const unsigned short* __restrict__ y0b, const float* __restrict__ sc0, const float* __restrict__ sh0,
    const unsigned short* __restrict__ w1b, const float* __restrict__ b1,
    unsigned short* __restrict__ y1, float2* __restrict__ part1)
{
  __shared__ __align__(16) unsigned short As[128][LP];
  __shared__ __align__(16) unsigned short Bs[128][LP];
  __shared__ float sredS[4][64], sredQ[4][64];
  const int l = blockIdx.x;
  const int tm = (l & 7) * (GM / 8) + (l >> 3);   // same bijective XCD swizzle as gemm0
  const int tid = threadIdx.x, lane = tid & 63, w = tid >> 6;
  const int wr = w >> 1, wc = w & 1;
  const int row0 = tm * 128;
  const int seg = tid & 7, rt = tid >> 3;
  const int ln = lane & 15, lg = lane >> 4;
  f32x4 acc[4][4] = {};
  for (int k0 = 0; k0 < H0; k0 += 64) {
    const float4 sA = *(const float4*)(sc0 + k0 + seg * 8);
    const float4 sB = *(const float4*)(sc0 + k0 + seg * 8 + 4);
    const float4 hA = *(const float4*)(sh0 + k0 + seg * 8);
    const float4 hB = *(const float4*)(sh0 + k0 + seg * 8 + 4);
    #pragma unroll
    for (int p = 0; p < 4; ++p) {
      const int r = rt + 32 * p;
      const ushort8v uy = *(const ushort8v*)(y0b + (size_t)(row0 + r) * H0 + k0 + seg * 8);
      ushort8v u;
      u[0] = bf16_rne(fmaxf(fmaf(bf16_to_f32(uy[0]), sA.x, hA.x), 0.f));
      u[1] = bf16_rne(fmaxf(fmaf(bf16_to_f32(uy[1]), sA.y, hA.y), 0.f));
      u[2] = bf16_rne(fmaxf(fmaf(bf16_to_f32(uy[2]), sA.z, hA.z), 0.f));
      u[3] = bf16_rne(fmaxf(fmaf(bf16_to_f32(uy[3]), sA.w, hA.w), 0.f));
      u[4] = bf16_rne(fmaxf(fmaf(bf16_to_f32(uy[4]), sB.x, hB.x), 0.f));
      u[5] = bf16_rne(fmaxf(fmaf(bf16_to_f32(uy[5]), sB.y, hB.y), 0.f));
      u[6] = bf16_rne(fmaxf(fmaf(bf16_to_f32(uy[6]), sB.z, hB.z), 0.f));
      u[7] = bf16_rne(fmaxf(fmaf(bf16_to_f32(uy[7]), sB.w, hB.w), 0.f));
      *(ushort8v*)&As[r][seg * 8] = u;
      *(uint4*)&Bs[r][seg * 8] = *(const uint4*)(w1b + (size_t)r * H0 + k0 + seg * 8);
    }
    __syncthreads();
    #pragma unroll
    for (int kb = 0; kb < 2; ++kb) {
      bf16x8 af[4], bf[4];
      #pragma unroll
      for (int i = 0; i < 4; ++i)
        af[i] = *(const bf16x8*)&As[wr * 64 + i * 16 + ln][kb * 32 + lg * 8];
      #pragma unroll
      for (int j = 0; j < 4; ++j)
        bf[j] = *(const bf16x8*)&Bs[wc * 64 + j * 16 + ln][kb * 32 + lg * 8];
      #pragma unroll
      for (int i = 0; i < 4; ++i)
        #pragma unroll
        for (int j = 0; j < 4; ++j)
          acc[i][j] = __builtin_amdgcn_mfma_f32_16x16x32_bf16(af[i], bf[j], acc[i][j], 0, 0, 0);
    }
    __syncthreads();
  }
  float colS[4] = {0, 0, 0, 0}, colQ[4] = {0, 0, 0, 0};
  #pragma unroll
  for (int j = 0; j < 4; ++j) {
    const int gc = wc * 64 + j * 16 + ln;
    const float bias = b1[gc];
    #pragma unroll
    for (int i = 0; i < 4; ++i) {
      const int grow = row0 + wr * 64 + i * 16 + lg * 4;
      #pragma unroll
      for (int q = 0; q < 4; ++q) {
        const float v = acc[i][j][q] + bias;
        y1[(size_t)(grow + q) * H1 + gc] = bf16_rne(v);
        colS[j] += v; colQ[j] = fmaf(v, v, colQ[j]);
      }
    }
  }
  #pragma unroll
  for (int j = 0; j < 4; ++j) {
    colS[j] += __shfl_xor(colS[j], 16, 64);
    colS[j] += __shfl_xor(colS[j], 32, 64);
    colQ[j] += __shfl_xor(colQ[j], 16, 64);
    colQ[j] += __shfl_xor(colQ[j], 32, 64);
  }
  if (lg == 0) {
    #pragma unroll
    for (int j = 0; j < 4; ++j) { sredS[w][j * 16 + ln] = colS[j]; sredQ[w][j * 16 + ln] = colQ[j]; }
  }
  __syncthreads();
  if (tid < 128) {
    const int ch = tid >> 6, cl = tid & 63;
    const float S = sredS[ch][cl] + sredS[2 + ch][cl];
    const float Q = sredQ[ch][cl] + sredQ[2 + ch][cl];
    part1[(size_t)tid * GM + tm] = make_float2(S, Q);
  }
}

// ---------------- Final BN1 + ReLU (bf16 y1 -> fp32 out) ----------------
__global__ __launch_bounds__(256) void bnrelu_out_kernel(
    const unsigned short* __restrict__ y1, const float* __restrict__ sc1,
    const float* __restrict__ sh1, float* __restrict__ out)
{
  const size_t i = (size_t)blockIdx.x * 256 + threadIdx.x;  // ushort8 unit (8 channels)
  const int c8 = (int)(i & (H1 / 8 - 1));
  const ushort8v u = ((const ushort8v*)y1)[i];
  const float4 s0 = ((const float4*)sc1)[c8 * 2], s1 = ((const float4*)sc1)[c8 * 2 + 1];
  const float4 h0 = ((const float4*)sh1)[c8 * 2], h1 = ((const float4*)sh1)[c8 * 2 + 1];
  float4 o0, o1;
  o0.x = fmaxf(fmaf(bf16_to_f32(u[0]), s0.x, h0.x), 0.f);
  o0.y = fmaxf(fmaf(bf16_to_f32(u[1]), s0.y, h0.y), 0.f);
  o0.z = fmaxf(fmaf(bf16_to_f32(u[2]), s0.z, h0.z), 0.f);
  o0.w = fmaxf(fmaf(bf16_to_f32(u[3]), s0.w, h0.w), 0.f);
  o1.x = fmaxf(fmaf(bf16_to_f32(u[4]), s1.x, h1.x), 0.f);
  o1.y = fmaxf(fmaf(bf16_to_f32(u[5]), s1.y, h1.y), 0.f);
  o1.z = fmaxf(fmaf(bf16_to_f32(u[6]), s1.z, h1.z), 0.f);
  o1.w = fmaxf(fmaf(bf16_to_f32(u[7]), s1.w, h1.w), 0.f);
  ((float4*)out)[2 * i] = o0;
  ((float4*)out)[2 * i + 1] = o1;
}

extern "C" void kernel_launch(void* const* d_in, const int* in_sizes, int n_in,
                              void* d_out, int out_size, void* d_ws, size_t ws_size,
                              hipStream_t stream)
{
  const float* xyz1  = (const float*)d_in[0];
  const float* xyz2  = (const float*)d_in[1];
  const float* feat1 = (const float*)d_in[2];
  const float* feat2 = (const float*)d_in[3];
  const float* W0  = (const float*)d_in[4];
  const float* b0  = (const float*)d_in[5];
  const float* g0  = (const float*)d_in[6];
  const float* be0 = (const float*)d_in[7];
  const float* W1  = (const float*)d_in[8];
  const float* b1  = (const float*)d_in[9];
  const float* g1  = (const float*)d_in[10];
  const float* be1 = (const float*)d_in[11];
  float* out = (float*)d_out;

  // workspace layout (~60 MB) — every buffer has exactly ONE writer kernel (no aliasing)
  char* ws = (char*)d_ws;
  size_t off = 0;
  unsigned short* y0b = (unsigned short*)(ws + off); off += (size_t)MT * H0 * 2;      // 33.5 MB
  unsigned short* y1  = (unsigned short*)(ws + off); off += (size_t)MT * H1 * 2;      // 16.8 MB
  float2* cand = (float2*)(ws + off); off += (size_t)MT * NCHUNK * 3 * 8;             // 6.3 MB
  int*   kidx = (int*)(ws + off);  off += (size_t)MT * 3 * 4;
  float* kw   = (float*)(ws + off); off += (size_t)MT * 3 * 4;
  float2* part0 = (float2*)(ws + off); off += (size_t)H0 * GM * 8;
  float2* part1 = (float2*)(ws + off); off += (size_t)H1 * GM * 8;
  unsigned short* w0b = (unsigned short*)(ws + off); off += (size_t)H0 * KC * 2;
  unsigned short* w1b = (unsigned short*)(ws + off); off += (size_t)H1 * H0 * 2;
  float* sc0 = (float*)(ws + off); off += H0 * 4;
  float* sh0 = (float*)(ws + off); off += H0 * 4;
  float* sc1 = (float*)(ws + off); off += H1 * 4;
  float* sh1 = (float*)(ws + off); off += H1 * 4;

  knn_chunk_kernel<<<dim3(NP1 / 256, NB, NCHUNK), 256, 0, stream>>>(xyz1, xyz2, cand);
  merge_cast_kernel<<<dim3(MT / 256 + (H0 * KC / 8 + H1 * H0 / 8) / 256), 256, 0, stream>>>(
      cand, kidx, kw, W0, W1, w0b, w1b);
  gemm0_mfma_kernel<<<dim3(GM), 512, 0, stream>>>(feat1, feat2, kidx, kw, w0b, b0, y0b, part0);
  bnfin_kernel<<<dim3(H0), 256, 0, stream>>>(part0, g0, be0, sc0, sh0);
  gemm1_mfma_kernel<<<dim3(GM), 256, 0, stream>>>(y0b, sc0, sh0, w1b, b1, y1, part1);
  bnfin_kernel<<<dim3(H1), 256, 0, stream>>>(part1, g1, be1, sc1, sh1);
  bnrelu_out_kernel<<<dim3(MT * H1 / 8 / 256), 256, 0, stream>>>(y1, sc1, sh1, out);
}

// Round 19
// 129.919 us; speedup vs baseline: 1.1453x; 1.0113x over previous
//
#include <hip/hip_runtime.h>
#include <hip/hip_bf16.h>
#include <math.h>

// FPLayer: 3-NN inverse-distance interpolation + concat + 2x (Conv1d(k=1) -> BN(train) -> ReLU)
// B=8 N1=8192 N2=2048 C1=128 C2=256 MLP=[256,128]
// Round 19: r18 exact, knn scan loop unroll 4 -> 8 (ILP probe; semantics identical).

#define NB 8
#define NP1 8192
#define NP2 2048
#define C1 128
#define C2 256
#define KC (C1 + C2)    // 384
#define H0 256
#define H1 128
#define MT (NB * NP1)   // 65536 rows
#define GM (MT / 128)   // 512 m-tiles
#define BN_EPS 1e-5f
#define NCHUNK 4
#define CHSZ (NP2 / NCHUNK)   // 512
#define LP 72           // padded LDS K-stride (ushorts): 144B rows -> 2-way bank alias (free)

typedef __attribute__((ext_vector_type(8))) short bf16x8;
typedef __attribute__((ext_vector_type(4))) float f32x4;
typedef __attribute__((ext_vector_type(8))) unsigned short ushort8v;
typedef __attribute__((ext_vector_type(4))) unsigned short ushort4v;

__device__ __forceinline__ unsigned short bf16_rne(float x) {
  unsigned int u = __float_as_uint(x);
  u += 0x7FFFu + ((u >> 16) & 1u);   // round-to-nearest-even on bf16 boundary
  return (unsigned short)(u >> 16);
}
__device__ __forceinline__ float bf16_to_f32(unsigned short u) {
  return __uint_as_float(((unsigned int)u) << 16);
}

// ---------------- KNN phase 1: per-chunk top-3 candidates (hybrid insert, fma dist) ----------------
__global__ __launch_bounds__(256) void knn_chunk_kernel(
    const float* __restrict__ xyz1, const float* __restrict__ xyz2,
    float2* __restrict__ cand)
{
  __shared__ __align__(16) float4 s2[CHSZ];   // {x, y, z, |p|^2/2}  8 KB
  const int b = blockIdx.y, c = blockIdx.z;
  const float* p2 = xyz2 + ((size_t)b * NP2 + c * CHSZ) * 3;
  for (int j = threadIdx.x; j < CHSZ; j += 256) {
    float x = p2[j * 3 + 0], y = p2[j * 3 + 1], z = p2[j * 3 + 2];
    float sq = __fadd_rn(__fadd_rn(__fmul_rn(x, x), __fmul_rn(y, y)), __fmul_rn(z, z));
    s2[j] = make_float4(x, y, z, 0.5f * sq);   // /2 exact
  }
  __syncthreads();
  const int n = blockIdx.x * 256 + threadIdx.x;
  const float* p1 = xyz1 + ((size_t)b * NP1 + n) * 3;
  const float ax = p1[0], ay = p1[1], az = p1[2];
  const float sq1 = __fadd_rn(__fadd_rn(__fmul_rn(ax, ax), __fmul_rn(ay, ay)), __fmul_rn(az, az));
  const float hsq1 = 0.5f * sq1;   // exact
  float b0v = 3.4e38f, b1v = 3.4e38f, b2v = 3.4e38f;
  int i0 = 0, i1 = 0, i2 = 0;
  #pragma unroll 8
  for (int j = 0; j < CHSZ; ++j) {
    const float4 p = s2[j];
    // fma-chain halved distance (4 VALU; selection-compatible, validated r10-r18)
    float m = __fadd_rn(hsq1, p.w);
    m = fmaf(-az, p.z, m);
    m = fmaf(-ay, p.y, m);
    m = fmaf(-ax, p.x, m);
    if (m < b2v) {
      const bool lt1 = m < b1v, lt0 = m < b0v;
      b2v = lt1 ? b1v : m;
      i2  = lt1 ? i1  : j;
      b1v = lt0 ? b0v : (lt1 ? m : b1v);
      i1  = lt0 ? i0  : (lt1 ? j : i1);
      b0v = lt0 ? m : b0v;
      i0  = lt0 ? j : i0;
    }
  }
  const int jb = c * CHSZ;
  const size_t o = (((size_t)b * NP1 + n) * NCHUNK + c) * 3;
  cand[o + 0] = make_float2(b0v, __int_as_float(jb + i0));
  cand[o + 1] = make_float2(b1v, __int_as_float(jb + i1));
  cand[o + 2] = make_float2(b2v, __int_as_float(jb + i2));
}

// ---------------- fused: KNN merge (blocks 0..255) + weight casts (blocks 256..319) ----------------
__global__ __launch_bounds__(256) void merge_cast_kernel(
    const float2* __restrict__ cand, int* __restrict__ knn_idx, float* __restrict__ knn_w,
    const float* __restrict__ W0, const float* __restrict__ W1,
    unsigned short* __restrict__ w0b, unsigned short* __restrict__ w1b)
{
  const int tid = threadIdx.x;
  if (blockIdx.x < MT / 256) {
    // ---- merge 4x3 candidates, compute weights ----
    const int m = blockIdx.x * 256 + tid;
    const float2* cc = cand + (size_t)m * (NCHUNK * 3);
    float b0v = 3.4e38f, b1v = 3.4e38f, b2v = 3.4e38f;
    int i0 = 0, i1 = 0, i2 = 0;
    #pragma unroll
    for (int t = 0; t < NCHUNK * 3; ++t) {
      const float2 p = cc[t];
      const float d2 = p.x;
      const int j = __float_as_int(p.y);
      if (d2 < b2v) {
        if (d2 < b1v) {
          b2v = b1v; i2 = i1;
          if (d2 < b0v) { b1v = b0v; i1 = i0; b0v = d2; i0 = j; }
          else          { b1v = d2; i1 = j; }
        } else { b2v = d2; i2 = j; }
      }
    }
    // restore d2 = 2*m (exact) and apply the reference clamp before sqrt
    const float d0 = fmaxf(__fmul_rn(2.0f, b0v), 1e-12f);
    const float d1 = fmaxf(__fmul_rn(2.0f, b1v), 1e-12f);
    const float d2v = fmaxf(__fmul_rn(2.0f, b2v), 1e-12f);
    const float s0 = sqrtf(d0), s1 = sqrtf(d1), s2d = sqrtf(d2v);
    const float r0 = 1.0f / (s0 + 1e-8f), r1 = 1.0f / (s1 + 1e-8f), r2 = 1.0f / (s2d + 1e-8f);
    const float rs = __fadd_rn(__fadd_rn(r0, r1), r2);
    const size_t o = (size_t)m * 3;
    knn_idx[o] = i0; knn_idx[o + 1] = i1; knn_idx[o + 2] = i2;
    knn_w[o] = r0 / rs; knn_w[o + 1] = r1 / rs; knn_w[o + 2] = r2 / rs;
  } else {
    // ---- both weights fp32 -> bf16 ----
    const int i = (blockIdx.x - MT / 256) * 256 + tid;
    const int n0 = H0 * KC / 8;   // 12288
    const float* src; unsigned short* dst; int k;
    if (i < n0) { src = W0; dst = w0b; k = i; }
    else        { src = W1; dst = w1b; k = i - n0; }   // n1 = 4096
    const float4 a = ((const float4*)src)[2 * k], b = ((const float4*)src)[2 * k + 1];
    ushort8v u;
    u[0] = bf16_rne(a.x); u[1] = bf16_rne(a.y); u[2] = bf16_rne(a.z); u[3] = bf16_rne(a.w);
    u[4] = bf16_rne(b.x); u[5] = bf16_rne(b.y); u[6] = bf16_rne(b.z); u[7] = bf16_rne(b.w);
    *(ushort8v*)(dst + (size_t)k * 8) = u;
  }
}

// ---------------- GEMM0: y0 = [feat1 | interp(feat2)] @ W0^T + b0, 128x256 tile, 8 waves ----
// grid (GM). XCD-swizzled: tm = (l&7)*64 + l>>3  (512%8==0 -> bijective). Batch b's 64
// m-tiles land on XCD b -> feat2 gathers stay in that XCD's 4MB L2 (2MB slice).
__global__ __launch_bounds__(512) void gemm0_mfma_kernel(
    const float* __restrict__ feat1, const float* __restrict__ feat2,
    const int* __restrict__ knn_idx, const float* __restrict__ knn_w,
    const unsigned short* __restrict__ w0b, const float* __restrict__ b0,
    unsigned short* __restrict__ y0b, float2* __restrict__ part0)
{
  __shared__ __align__(16) unsigned short As[128][LP];   // 18.4 KB
  __shared__ __align__(16) unsigned short Bs[256][LP];   // 36.9 KB
  __shared__ float sredS[8][64], sredQ[8][64];           // 4 KB
  const int l = blockIdx.x;
  const int tm = (l & 7) * (GM / 8) + (l >> 3);   // XCD-aware bijective swizzle
  const int tid = threadIdx.x, lane = tid & 63, w = tid >> 6;
  const int wr = w >> 2, wc = w & 3;
  const int row0 = tm * 128;
  const int seg = tid & 7, rt = tid >> 3;   // rt in [0,64)
  const int ln = lane & 15, lg = lane >> 4;

  // per-thread gather state for its 2 staged A-rows
  unsigned g0[2], g1[2], g2[2];
  float gw0[2], gw1[2], gw2[2];
  #pragma unroll
  for (int p = 0; p < 2; ++p) {
    const int grow = row0 + rt + 64 * p;
    const size_t o3 = (size_t)grow * 3;
    const unsigned base = (unsigned)(grow >> 13) * (NP2 * C2);
    g0[p] = base + (unsigned)knn_idx[o3]     * C2;
    g1[p] = base + (unsigned)knn_idx[o3 + 1] * C2;
    g2[p] = base + (unsigned)knn_idx[o3 + 2] * C2;
    gw0[p] = knn_w[o3]; gw1[p] = knn_w[o3 + 1]; gw2[p] = knn_w[o3 + 2];
  }

  f32x4 acc[4][4] = {};
  for (int k0 = 0; k0 < KC; k0 += 64) {
    if (k0 < C1) {   // feat1 fp32 -> bf16 staging (2 rows/thread)
      #pragma unroll
      for (int p = 0; p < 2; ++p) {
        const int r = rt + 64 * p;
        const float* src = feat1 + (size_t)(row0 + r) * C1 + k0 + seg * 8;
        const float4 va = *(const float4*)src, vb = *(const float4*)(src + 4);
        ushort8v u;
        u[0] = bf16_rne(va.x); u[1] = bf16_rne(va.y); u[2] = bf16_rne(va.z); u[3] = bf16_rne(va.w);
        u[4] = bf16_rne(vb.x); u[5] = bf16_rne(vb.y); u[6] = bf16_rne(vb.z); u[7] = bf16_rne(vb.w);
        *(ushort8v*)&As[r][seg * 8] = u;
      }
    } else {         // fused interp staging: gather 3 neighbor rows, weight, cast
      const int ch = (k0 - C1) + seg * 8;
      #pragma unroll
      for (int p = 0; p < 2; ++p) {
        const int r = rt + 64 * p;
        const float4* f0p = (const float4*)(feat2 + (size_t)g0[p] + ch);
        const float4* f1p = (const float4*)(feat2 + (size_t)g1[p] + ch);
        const float4* f2p = (const float4*)(feat2 + (size_t)g2[p] + ch);
        const float4 a0 = f0p[0], a1 = f0p[1];
        const float4 e0 = f1p[0], e1 = f1p[1];
        const float4 c0 = f2p[0], c1 = f2p[1];
        const float w0v = gw0[p], w1v = gw1[p], w2v = gw2[p];
        ushort8v u;
        u[0] = bf16_rne(w0v * a0.x + w1v * e0.x + w2v * c0.x);
        u[1] = bf16_rne(w0v * a0.y + w1v * e0.y + w2v * c0.y);
        u[2] = bf16_rne(w0v * a0.z + w1v * e0.z + w2v * c0.z);
        u[3] = bf16_rne(w0v * a0.w + w1v * e0.w + w2v * c0.w);
        u[4] = bf16_rne(w0v * a1.x + w1v * e1.x + w2v * c1.x);
        u[5] = bf16_rne(w0v * a1.y + w1v * e1.y + w2v * c1.y);
        u[6] = bf16_rne(w0v * a1.z + w1v * e1.z + w2v * c1.z);
        u[7] = bf16_rne(w0v * a1.w + w1v * e1.w + w2v * c1.w);
        *(ushort8v*)&As[r][seg * 8] = u;
      }
    }
    // B staging: 4 rows/thread (256 output channels)
    #pragma unroll
    for (int p = 0; p < 4; ++p) {
      const int r = rt + 64 * p;
      *(uint4*)&Bs[r][seg * 8] = *(const uint4*)(w0b + (size_t)r * KC + k0 + seg * 8);
    }
    __syncthreads();
    #pragma unroll
    for (int kb = 0; kb < 2; ++kb) {
      bf16x8 af[4], bf[4];
      #pragma unroll
      for (int i = 0; i < 4; ++i)
        af[i] = *(const bf16x8*)&As[wr * 64 + i * 16 + ln][kb * 32 + lg * 8];
      #pragma unroll
      for (int j = 0; j < 4; ++j)
        bf[j] = *(const bf16x8*)&Bs[wc * 64 + j * 16 + ln][kb * 32 + lg * 8];
      #pragma unroll
      for (int i = 0; i < 4; ++i)
        #pragma unroll
        for (int j = 0; j < 4; ++j)
          acc[i][j] = __builtin_amdgcn_mfma_f32_16x16x32_bf16(af[i], bf[j], acc[i][j], 0, 0, 0);
    }
    __syncthreads();
  }
  // epilogue: bias, store y0 bf16, per-column BN partials from fp32 values
  float colS[4] = {0, 0, 0, 0}, colQ[4] = {0, 0, 0, 0};
  #pragma unroll
  for (int j = 0; j < 4; ++j) {
    const int gc = wc * 64 + j * 16 + ln;
    const float bias = b0[gc];
    #pragma unroll
    for (int i = 0; i < 4; ++i) {
      const int grow = row0 + wr * 64 + i * 16 + lg * 4;
      #pragma unroll
      for (int q = 0; q < 4; ++q) {
        const float v = acc[i][j][q] + bias;
        y0b[(size_t)(grow + q) * H0 + gc] = bf16_rne(v);
        colS[j] += v; colQ[j] = fmaf(v, v, colQ[j]);
      }
    }
  }
  #pragma unroll
  for (int j = 0; j < 4; ++j) {
    colS[j] += __shfl_xor(colS[j], 16, 64);
    colS[j] += __shfl_xor(colS[j], 32, 64);
    colQ[j] += __shfl_xor(colQ[j], 16, 64);
    colQ[j] += __shfl_xor(colQ[j], 32, 64);
  }
  if (lg == 0) {
    #pragma unroll
    for (int j = 0; j < 4; ++j) { sredS[w][j * 16 + ln] = colS[j]; sredQ[w][j * 16 + ln] = colQ[j]; }
  }
  __syncthreads();
  if (tid < 256) {   // column = tid; combine wr=0 and wr=1 partials
    const int wcc = tid >> 6, cl = tid & 63;
    const float S = sredS[wcc][cl] + sredS[4 + wcc][cl];
    const float Q = sredQ[wcc][cl] + sredQ[4 + wcc][cl];
    part0[(size_t)tid * GM + tm] = make_float2(S, Q);
  }
}

// ---------------- BN finalize: mean/var -> scale/shift ----------------
__global__ __launch_bounds__(256) void bnfin_kernel(
    const float2* __restrict__ part, const float* __restrict__ gamma,
    const float* __restrict__ beta, float* __restrict__ sc, float* __restrict__ sh)
{
  __shared__ float2 red[256];
  const int ch = blockIdx.x, tid = threadIdx.x;
  float s = 0.f, q = 0.f;
  for (int t = tid; t < GM; t += 256) {
    float2 p = part[(size_t)ch * GM + t];
    s += p.x; q += p.y;
  }
  red[tid] = make_float2(s, q);
  __syncthreads();
  for (int off = 128; off > 0; off >>= 1) {
    if (tid < off) { float2 o = red[tid + off]; red[tid].x += o.x; red[tid].y += o.y; }
    __syncthreads();
  }
  if (tid == 0) {
    const float mean = red[0].x / (float)MT;
    const float var  = red[0].y / (float)MT - mean * mean;
    const float scale = gamma[ch] / sqrtf(var + BN_EPS);
    sc[ch] = scale;
    sh[ch] = beta[ch] - mean * scale;
  }
}

// ---------------- GEMM1: y1 = relu(bn0(y0)) @ W1^T + b1 (bf16 MFMA), y1 stored bf16 ----------------
// grid (GM), XCD-swizzled like gemm0 so tile tm reads y0b from the XCD whose L2 holds it.
__global__ __launch_bounds__(256) void gemm1_mfma_kernel(
    const unsigned short* __restrict__ y0b, const float* __restrict__ sc0, const float* __restrict__ sh0,
    const unsigned short* __restrict__ w1b, const float* __restrict__ b1,
    unsigned short* __restrict__ y1, float2* __restrict__ part1)
{
  __shared__ __align__(16) unsigned short As[128][LP];
  __shared__ __align__(16) unsigned short Bs[128][LP];
  __shared__ float sredS[4][64], sredQ[4][64];
  const int l = blockIdx.x;
  const int tm = (l & 7) * (GM / 8) + (l >> 3);   // same bijective XCD swizzle as gemm0
  const int tid = threadIdx.x, lane = tid & 63, w = tid >> 6;
  const int wr = w >> 1, wc = w & 1;
  const int row0 = tm * 128;
  const int seg = tid & 7, rt = tid >> 3;
  const int ln = lane & 15, lg = lane >> 4;
  f32x4 acc[4][4] = {};
  for (int k0 = 0; k0 < H0; k0 += 64) {
    const float4 sA = *(const float4*)(sc0 + k0 + seg * 8);
    const float4 sB = *(const float4*)(sc0 + k0 + seg * 8 + 4);
    const float4 hA = *(const float4*)(sh0 + k0 + seg * 8);
    const float4 hB = *(const float4*)(sh0 + k0 + seg * 8 + 4);
    #pragma unroll
    for (int p = 0; p < 4; ++p) {
      const int r = rt + 32 * p;
      const ushort8v uy = *(const ushort8v*)(y0b + (size_t)(row0 + r) * H0 + k0 + seg * 8);
      ushort8v u;
      u[0] = bf16_rne(fmaxf(fmaf(bf16_to_f32(uy[0]), sA.x, hA.x), 0.f));
      u[1] = bf16_rne(fmaxf(fmaf(bf16_to_f32(uy[1]), sA.y, hA.y), 0.f));
      u[2] = bf16_rne(fmaxf(fmaf(bf16_to_f32(uy[2]), sA.z, hA.z), 0.f));
      u[3] = bf16_rne(fmaxf(fmaf(bf16_to_f32(uy[3]), sA.w, hA.w), 0.f));
      u[4] = bf16_rne(fmaxf(fmaf(bf16_to_f32(uy[4]), sB.x, hB.x), 0.f));
      u[5] = bf16_rne(fmaxf(fmaf(bf16_to_f32(uy[5]), sB.y, hB.y), 0.f));
      u[6] = bf16_rne(fmaxf(fmaf(bf16_to_f32(uy[6]), sB.z, hB.z), 0.f));
      u[7] = bf16_rne(fmaxf(fmaf(bf16_to_f32(uy[7]), sB.w, hB.w), 0.f));
      *(ushort8v*)&As[r][seg * 8] = u;
      *(uint4*)&Bs[r][seg * 8] = *(const uint4*)(w1b + (size_t)r * H0 + k0 + seg * 8);
    }
    __syncthreads();
    #pragma unroll
    for (int kb = 0; kb < 2; ++kb) {
      bf16x8 af[4], bf[4];
      #pragma unroll
      for (int i = 0; i < 4; ++i)
        af[i] = *(const bf16x8*)&As[wr * 64 + i * 16 + ln][kb * 32 + lg * 8];
      #pragma unroll
      for (int j = 0; j < 4; ++j)
        bf[j] = *(const bf16x8*)&Bs[wc * 64 + j * 16 + ln][kb * 32 + lg * 8];
      #pragma unroll
      for (int i = 0; i < 4; ++i)
        #pragma unroll
        for (int j = 0; j < 4; ++j)
          acc[i][j] = __builtin_amdgcn_mfma_f32_16x16x32_bf16(af[i], bf[j], acc[i][j], 0, 0, 0);
    }
    __syncthreads();
  }
  float colS[4] = {0, 0, 0, 0}, colQ[4] = {0, 0, 0, 0};
  #pragma unroll
  for (int j = 0; j < 4; ++j) {
    const int gc = wc * 64 + j * 16 + ln;
    const float bias = b1[gc];
    #pragma unroll
    for (int i = 0; i < 4; ++i) {
      const int grow = row0 + wr * 64 + i * 16 + lg * 4;
      #pragma unroll
      for (int q = 0; q < 4; ++q) {
        const float v = acc[i][j][q] + bias;
        y1[(size_t)(grow + q) * H1 + gc] = bf16_rne(v);
        colS[j] += v; colQ[j] = fmaf(v, v, colQ[j]);
      }
    }
  }
  #pragma unroll
  for (int j = 0; j < 4; ++j) {
    colS[j] += __shfl_xor(colS[j], 16, 64);
    colS[j] += __shfl_xor(colS[j], 32, 64);
    colQ[j] += __shfl_xor(colQ[j], 16, 64);
    colQ[j] += __shfl_xor(colQ[j], 32, 64);
  }
  if (lg == 0) {
    #pragma unroll
    for (int j = 0; j < 4; ++j) { sredS[w][j * 16 + ln] = colS[j]; sredQ[w][j * 16 + ln] = colQ[j]; }
  }
  __syncthreads();
  if (tid < 128) {
    const int ch = tid >> 6, cl = tid & 63;
    const float S = sredS[ch][cl] + sredS[2 + ch][cl];
    const float Q = sredQ[ch][cl] + sredQ[2 + ch][cl];
    part1[(size_t)tid * GM + tm] = make_float2(S, Q);
  }
}

// ---------------- Final BN1 + ReLU (bf16 y1 -> fp32 out) ----------------
__global__ __launch_bounds__(256) void bnrelu_out_kernel(
    const unsigned short* __restrict__ y1, const float* __restrict__ sc1,
    const float* __restrict__ sh1, float* __restrict__ out)
{
  const size_t i = (size_t)blockIdx.x * 256 + threadIdx.x;  // ushort8 unit (8 channels)
  const int c8 = (int)(i & (H1 / 8 - 1));
  const ushort8v u = ((const ushort8v*)y1)[i];
  const float4 s0 = ((const float4*)sc1)[c8 * 2], s1 = ((const float4*)sc1)[c8 * 2 + 1];
  const float4 h0 = ((const float4*)sh1)[c8 * 2], h1 = ((const float4*)sh1)[c8 * 2 + 1];
  float4 o0, o1;
  o0.x = fmaxf(fmaf(bf16_to_f32(u[0]), s0.x, h0.x), 0.f);
  o0.y = fmaxf(fmaf(bf16_to_f32(u[1]), s0.y, h0.y), 0.f);
  o0.z = fmaxf(fmaf(bf16_to_f32(u[2]), s0.z, h0.z), 0.f);
  o0.w = fmaxf(fmaf(bf16_to_f32(u[3]), s0.w, h0.w), 0.f);
  o1.x = fmaxf(fmaf(bf16_to_f32(u[4]), s1.x, h1.x), 0.f);
  o1.y = fmaxf(fmaf(bf16_to_f32(u[5]), s1.y, h1.y), 0.f);
  o1.z = fmaxf(fmaf(bf16_to_f32(u[6]), s1.z, h1.z), 0.f);
  o1.w = fmaxf(fmaf(bf16_to_f32(u[7]), s1.w, h1.w), 0.f);
  ((float4*)out)[2 * i] = o0;
  ((float4*)out)[2 * i + 1] = o1;
}

extern "C" void kernel_launch(void* const* d_in, const int* in_sizes, int n_in,
                              void* d_out, int out_size, void* d_ws, size_t ws_size,
                              hipStream_t stream)
{
  const float* xyz1  = (const float*)d_in[0];
  const float* xyz2  = (const float*)d_in[1];
  const float* feat1 = (const float*)d_in[2];
  const float* feat2 = (const float*)d_in[3];
  const float* W0  = (const float*)d_in[4];
  const float* b0  = (const float*)d_in[5];
  const float* g0  = (const float*)d_in[6];
  const float* be0 = (const float*)d_in[7];
  const float* W1  = (const float*)d_in[8];
  const float* b1  = (const float*)d_in[9];
  const float* g1  = (const float*)d_in[10];
  const float* be1 = (const float*)d_in[11];
  float* out = (float*)d_out;

  // workspace layout (~60 MB) — every buffer has exactly ONE writer kernel (no aliasing)
  char* ws = (char*)d_ws;
  size_t off = 0;
  unsigned short* y0b = (unsigned short*)(ws + off); off += (size_t)MT * H0 * 2;      // 33.5 MB
  unsigned short* y1  = (unsigned short*)(ws + off); off += (size_t)MT * H1 * 2;      // 16.8 MB
  float2* cand = (float2*)(ws + off); off += (size_t)MT * NCHUNK * 3 * 8;             // 6.3 MB
  int*   kidx = (int*)(ws + off);  off += (size_t)MT * 3 * 4;
  float* kw   = (float*)(ws + off); off += (size_t)MT * 3 * 4;
  float2* part0 = (float2*)(ws + off); off += (size_t)H0 * GM * 8;
  float2* part1 = (float2*)(ws + off); off += (size_t)H1 * GM * 8;
  unsigned short* w0b = (unsigned short*)(ws + off); off += (size_t)H0 * KC * 2;
  unsigned short* w1b = (unsigned short*)(ws + off); off += (size_t)H1 * H0 * 2;
  float* sc0 = (float*)(ws + off); off += H0 * 4;
  float* sh0 = (float*)(ws + off); off += H0 * 4;
  float* sc1 = (float*)(ws + off); off += H1 * 4;
  float* sh1 = (float*)(ws + off); off += H1 * 4;

  knn_chunk_kernel<<<dim3(NP1 / 256, NB, NCHUNK), 256, 0, stream>>>(xyz1, xyz2, cand);
  merge_cast_kernel<<<dim3(MT / 256 + (H0 * KC / 8 + H1 * H0 / 8) / 256), 256, 0, stream>>>(
      cand, kidx, kw, W0, W1, w0b, w1b);
  gemm0_mfma_kernel<<<dim3(GM), 512, 0, stream>>>(feat1, feat2, kidx, kw, w0b, b0, y0b, part0);
  bnfin_kernel<<<dim3(H0), 256, 0, stream>>>(part0, g0, be0, sc0, sh0);
  gemm1_mfma_kernel<<<dim3(GM), 256, 0, stream>>>(y0b, sc0, sh0, w1b, b1, y1, part1);
  bnfin_kernel<<<dim3(H1), 256, 0, stream>>>(part1, g1, be1, sc1, sh1);
  bnrelu_out_kernel<<<dim3(MT * H1 / 8 / 256), 256, 0, stream>>>(y1, sc1, sh1, out);
}